// Round 13
// baseline (234.485 us; speedup 1.0000x reference)
//
#include <hip/hip_runtime.h>

// LightGCN encoder on MI355X — round 20.
// Round 19 post-mortem: grain halving null on wall (223.5 ~ 223.7) AND one
// 31-ms build_csr instance under rocprof replay (likely artifact, but not
// worth keeping) -> reverted to r18 grain (BUCKET=256, clean profile).
// Last live lever: pull MLP. lane=dim pull issues ~8 independent row loads
// per wave; ~320 outstanding lines/CU x ~700ns latency models the observed
// 44.5 us (latency-MLP bound; VALU 25%, HBM 32%). This round: TWO nodes per
// wave, interleaved quad loop (uniform guards, no divergence) -> ~16 loads
// in flight. Per-node accumulation order bit-identical (absmax unchanged).
// Pre-commitment: pull >= 43 us -> request capacity saturated -> ROOFLINE.
#define N_USERS 100000
#define N_NODES 150000
#define DIM 64
#define BATCH 4096
#define BSHIFT 8
#define BUCKET 256
#define NB 586                 // ceil(150000 / 256) buckets
#define NBP 768                // padded bucket count for the 3-per-thread scan
#define PAIRS_PER_BLK 2048     // undirected pairs per binning block
#define STRIP 4096             // directed edges (words) per strip
#define CAPSHIFT 13
#define CAP (1 << CAPSHIFT)    // packed slots per bucket (max ~5.4K used)

typedef unsigned short bf16_t;

static __device__ __forceinline__ float bf2f(bf16_t h) {
    return __uint_as_float(((unsigned)h) << 16);
}
static __device__ __forceinline__ bf16_t f2bf(float f) {  // round-nearest-even
    unsigned u = __float_as_uint(f);
    return (bf16_t)((u + 0x7FFFu + ((u >> 16) & 1u)) >> 16);
}

// --- Strip sort: LDS counting-sort of 4096 directed edges by bucket --------
// binned word = (local_dst[8b]<<18)|src. pos[k*(NB+1)+b] = run start of
// bucket b in strip k; pos[k*(NB+1)+NB] = edge count of strip k.
__global__ void __launch_bounds__(256)
lgcn_bin(const int* __restrict__ row, const int* __restrict__ col,
         int* __restrict__ pos, int* __restrict__ binned, int EH) {
    __shared__ int cnt[NBP];
    __shared__ int sA[256], sB[256];
    __shared__ int base[NB + 2];
    __shared__ int stage[STRIP];
    int tid = threadIdx.x;
    int k = blockIdx.x;
    cnt[tid] = 0; cnt[tid + 256] = 0; cnt[tid + 512] = 0;
    __syncthreads();
    int e0 = k * PAIRS_PER_BLK;
    int e1 = min(EH, e0 + PAIRS_PER_BLK);
    int n = e1 - e0;                           // pairs (multiple of 4)
    int nq = n >> 2;
    const int4* r4 = (const int4*)(row + e0);
    const int4* c4 = (const int4*)(col + e0);
    for (int q = tid; q < nq; q += 256) {
        int4 r = r4[q]; int4 c = c4[q];
        atomicAdd(&cnt[r.x >> BSHIFT], 1); atomicAdd(&cnt[c.x >> BSHIFT], 1);
        atomicAdd(&cnt[r.y >> BSHIFT], 1); atomicAdd(&cnt[c.y >> BSHIFT], 1);
        atomicAdd(&cnt[r.z >> BSHIFT], 1); atomicAdd(&cnt[c.z >> BSHIFT], 1);
        atomicAdd(&cnt[r.w >> BSHIFT], 1); atomicAdd(&cnt[c.w >> BSHIFT], 1);
    }
    __syncthreads();
    // Exclusive scan over NBP buckets, 3 per thread.
    int c0 = cnt[3 * tid], c1 = cnt[3 * tid + 1], c2 = cnt[3 * tid + 2];
    int s = c0 + c1 + c2;
    sA[tid] = s;
    __syncthreads();
    int* c_ = sA; int* n_ = sB;
    for (int off = 1; off < 256; off <<= 1) {
        n_[tid] = (tid >= off) ? c_[tid] + c_[tid - off] : c_[tid];
        __syncthreads();
        int* t = c_; c_ = n_; n_ = t;
    }
    int excl = c_[tid] - s;
    if (3 * tid     <= NB) base[3 * tid]     = excl;
    if (3 * tid + 1 <= NB) base[3 * tid + 1] = excl + c0;
    if (3 * tid + 2 <= NB) base[3 * tid + 2] = excl + c0 + c1;
    __syncthreads();
    // pos table (coalesced) + LDS cursors (reuse cnt).
    for (int i = tid; i <= NB; i += 256) {
        pos[k * (NB + 1) + i] = base[i];
        cnt[i] = base[i];
    }
    __syncthreads();
    // LDS scatter (re-read pairs; L2-hot).
    for (int q = tid; q < nq; q += 256) {
        int4 r = r4[q]; int4 c = c4[q];
        int rr[4] = { r.x, r.y, r.z, r.w };
        int cc[4] = { c.x, c.y, c.z, c.w };
#pragma unroll
        for (int j = 0; j < 4; ++j) {
            int p1 = atomicAdd(&cnt[cc[j] >> BSHIFT], 1);
            stage[p1] = ((cc[j] & (BUCKET - 1)) << 18) | rr[j];
            int p2 = atomicAdd(&cnt[rr[j] >> BSHIFT], 1);
            stage[p2] = ((rr[j] & (BUCKET - 1)) << 18) | cc[j];
        }
    }
    __syncthreads();
    // Coalesced strip write-out.
    int m4 = (2 * n) >> 2;
    int4* dst = (int4*)(binned + k * STRIP);
    const int4* st4 = (const int4*)stage;
    for (int j = tid; j < m4; j += 256) dst[j] = st4[j];
}

// --- Per-bucket padded CSR + fused g0 init ---------------------------------
// Phase A: flattened gather (runStart/runAddr + binary search, independent
// coalesced-ish loads). Phase B: hist/scan/scatter + g0 init.
// Node segments padded to multiple of 4; pad slots = N_NODES (zero row).
// nodeinfo = {start, deg, bits(1/sqrt(da)), bits(sqrt(da))}.
__global__ void __launch_bounds__(256)
lgcn_build_csr(const int* __restrict__ pos, const int* __restrict__ binned,
               int4* __restrict__ nodeinfo, int* __restrict__ packed,
               const float* __restrict__ ue, const float* __restrict__ ie,
               bf16_t* __restrict__ g0, bf16_t* __restrict__ g1, int nblk) {
    __shared__ int stage[CAP];     // gathered edges of this bucket (32 KB)
    __shared__ int ovl[1025];      // phase A: runStart[513] + runAddr[512]
                                   // phase B: hist[256] + cur[256]
    __shared__ int sA[256], sB[256];
    int b = blockIdx.x;
    int tid = threadIdx.x;
    int gb = b << CAPSHIFT;        // this block's private packed region
    int* runStart = ovl;
    int* runAddr  = ovl + 513;
    // Runs for strips 2*tid and 2*tid+1 (adjacent -> contiguous flat order).
    int s0 = 2 * tid, s1 = 2 * tid + 1;
    int a0 = 0, l0 = 0, a1 = 0, l1 = 0;
    if (s0 < nblk) {
        const int* pk = pos + s0 * (NB + 1) + b;
        a0 = pk[0]; l0 = pk[1] - a0;
    }
    if (s1 < nblk) {
        const int* pk = pos + s1 * (NB + 1) + b;
        a1 = pk[0]; l1 = pk[1] - a1;
    }
    runAddr[s0] = s0 * STRIP + a0;
    runAddr[s1] = s1 * STRIP + a1;
    int u = l0 + l1;
    sA[tid] = u;
    __syncthreads();
    int* c_ = sA; int* n_ = sB;
    for (int off = 1; off < 256; off <<= 1) {
        n_[tid] = (tid >= off) ? c_[tid] + c_[tid - off] : c_[tid];
        __syncthreads();
        int* t = c_; c_ = n_; n_ = t;
    }
    int base2 = c_[tid] - u;
    runStart[s0] = base2;
    runStart[s1] = base2 + l0;
    int Eb = c_[255];
    if (tid == 0) runStart[512] = Eb;
    __syncthreads();
    // Flattened gather: independent loads, consecutive j coalesce in runs.
    for (int j = tid; j < Eb; j += 256) {
        int lo = 0;                           // largest s: runStart[s] <= j
#pragma unroll
        for (int step = 256; step > 0; step >>= 1) {
            int mid = lo + step;
            if (mid <= 511 && runStart[mid] <= j) lo = mid;
        }
        stage[j] = binned[runAddr[lo] + (j - runStart[lo])];
    }
    __syncthreads();                          // runStart/runAddr dead
    int* hist = ovl;                          // overlay phase B
    int* cur  = ovl + 256;
    hist[tid] = 0;
    __syncthreads();
    for (int j = tid; j < Eb; j += 256)
        atomicAdd(&hist[stage[j] >> 18], 1);
    __syncthreads();
    int deg = hist[tid];
    int degp = (deg + 3) & ~3;               // padded segment length
    sA[tid] = degp;
    __syncthreads();
    int* c2 = sA; int* n2 = sB;
    for (int off = 1; off < 256; off <<= 1) {
        n2[tid] = (tid >= off) ? c2[tid] + c2[tid - off] : c2[tid];
        __syncthreads();
        int* t = c2; c2 = n2; n2 = t;
    }
    int startLoc = c2[tid] - degp;           // local, int4-aligned
    cur[tid] = startLoc;
    int node = (b << BSHIFT) + tid;
    float da = (deg == 0) ? 1.0f : (float)deg;
    float sq = sqrtf(da);
    float nm = 1.0f / sq;
    if (node < N_NODES) {
        int4 ni;
        ni.x = gb + startLoc;
        ni.y = deg;
        ni.z = __float_as_int(nm);
        ni.w = __float_as_int(sq);
        nodeinfo[node] = ni;
    }
    __syncthreads();                          // all hist reads done
    hist[tid] = __float_as_int(nm);           // reuse hist as norm table
    // Pad slots -> zero row (block-owned region; disjoint from scatter).
    for (int kk = deg; kk < degp; ++kk)
        packed[gb + startLoc + kk] = N_NODES;
    // Direct global scatter into the block's private bucket region.
    for (int j = tid; j < Eb; j += 256) {
        int w = stage[j];
        int p = atomicAdd(&cur[w >> 18], 1);  // LDS atomic
        packed[gb + p] = w & 0x3FFFF;
    }
    // --- Fused g0 init for this bucket's nodes (flat chunk range is
    // contiguous: t = b*4096 + i, i in [0, nloc*16)). -----------------------
    int firstNode = b << BSHIFT;
    int nloc = min(BUCKET, N_NODES - firstNode);
    const int nU16 = N_USERS * (DIM / 4);
    int t0 = firstNode * (DIM / 4);
    for (int i = tid; i < nloc * (DIM / 4); i += 256) {
        int t = t0 + i;
        float4 x = (t < nU16) ? ((const float4*)ue)[t]
                              : ((const float4*)ie)[t - nU16];
        float nrm = __int_as_float(hist[i >> 4]);
        ushort4 o;
        o.x = f2bf(x.x * nrm); o.y = f2bf(x.y * nrm);
        o.z = f2bf(x.z * nrm); o.w = f2bf(x.w * nrm);
        ((ushort4*)g0)[t] = o;
    }
    if (b == 0 && tid < 32) {                 // zero rows in both buffers
        const int nT = N_NODES * (DIM / 4);
        if (tid < 16) ((ushort4*)g0)[nT + tid] = make_ushort4(0, 0, 0, 0);
        else          ((ushort4*)g1)[nT + tid - 16] = make_ushort4(0, 0, 0, 0);
    }
}

// --- Propagation (lane = dim) ----------------------------------------------

// Single-segment gather (used by lgcn_final).
static __device__ __forceinline__ float
gather_lane(const bf16_t* __restrict__ g, const int* __restrict__ packed,
            int su, int dp, int lane) {
    float acc = 0.f;
    const int4* p4 = (const int4*)(packed + su);
    int k = 0;
    for (; k + 8 <= dp; k += 8) {            // 8 independent row loads
        int4 ea = p4[k >> 2];
        int4 eb = p4[(k >> 2) + 1];
        const bf16_t* r0 = g + ((unsigned)ea.x << 6);
        const bf16_t* r1 = g + ((unsigned)ea.y << 6);
        const bf16_t* r2 = g + ((unsigned)ea.z << 6);
        const bf16_t* r3 = g + ((unsigned)ea.w << 6);
        const bf16_t* r4 = g + ((unsigned)eb.x << 6);
        const bf16_t* r5 = g + ((unsigned)eb.y << 6);
        const bf16_t* r6 = g + ((unsigned)eb.z << 6);
        const bf16_t* r7 = g + ((unsigned)eb.w << 6);
        float v0 = bf2f(r0[lane]); float v1 = bf2f(r1[lane]);
        float v2 = bf2f(r2[lane]); float v3 = bf2f(r3[lane]);
        float v4 = bf2f(r4[lane]); float v5 = bf2f(r5[lane]);
        float v6 = bf2f(r6[lane]); float v7 = bf2f(r7[lane]);
        acc += ((v0 + v1) + (v2 + v3)) + ((v4 + v5) + (v6 + v7));
    }
    if (k < dp) {                            // tail quad (dp % 8 == 4)
        int4 ea = p4[k >> 2];
        const bf16_t* r0 = g + ((unsigned)ea.x << 6);
        const bf16_t* r1 = g + ((unsigned)ea.y << 6);
        const bf16_t* r2 = g + ((unsigned)ea.z << 6);
        const bf16_t* r3 = g + ((unsigned)ea.w << 6);
        float v0 = bf2f(r0[lane]); float v1 = bf2f(r1[lane]);
        float v2 = bf2f(r2[lane]); float v3 = bf2f(r3[lane]);
        acc += (v0 + v1) + (v2 + v3);
    }
    return acc;
}

// Dual-segment interleaved gather: two independent load streams per wave
// (~16 row loads in flight with unroll 2). All guards wave-uniform.
// Per-node accumulation order identical to gather_lane quad order.
static __device__ __forceinline__ void
gather_lane2(const bf16_t* __restrict__ g, const int* __restrict__ packed,
             int su0, int dp0, int su1, int dp1, int lane,
             float& a0, float& a1) {
    const int4* p0 = (const int4*)(packed + su0);
    const int4* p1 = (const int4*)(packed + su1);
    int dm = max(dp0, dp1);
#pragma unroll 2
    for (int k = 0; k < dm; k += 4) {
        if (k < dp0) {
            int4 e = p0[k >> 2];
            const bf16_t* r0 = g + ((unsigned)e.x << 6);
            const bf16_t* r1 = g + ((unsigned)e.y << 6);
            const bf16_t* r2 = g + ((unsigned)e.z << 6);
            const bf16_t* r3 = g + ((unsigned)e.w << 6);
            float v0 = bf2f(r0[lane]); float v1 = bf2f(r1[lane]);
            float v2 = bf2f(r2[lane]); float v3 = bf2f(r3[lane]);
            a0 += (v0 + v1) + (v2 + v3);
        }
        if (k < dp1) {
            int4 e = p1[k >> 2];
            const bf16_t* r0 = g + ((unsigned)e.x << 6);
            const bf16_t* r1 = g + ((unsigned)e.y << 6);
            const bf16_t* r2 = g + ((unsigned)e.z << 6);
            const bf16_t* r3 = g + ((unsigned)e.w << 6);
            float v0 = bf2f(r0[lane]); float v1 = bf2f(r1[lane]);
            float v2 = bf2f(r2[lane]); float v3 = bf2f(r3[lane]);
            a1 += (v0 + v1) + (v2 + v3);
        }
    }
}

// Full pull, TWO nodes per wave (lane = dim):
// gn[n] = bf16( norm[n]^2 * sum_{s in N(n)} g[s] ).
__global__ void __launch_bounds__(256)
lgcn_pull(const bf16_t* __restrict__ g, const int4* __restrict__ nodeinfo,
          const int* __restrict__ packed, bf16_t* __restrict__ gn) {
    int gw = blockIdx.x * 4 + (threadIdx.x >> 6);
    int n0 = gw * 2;
    if (n0 >= N_NODES) return;
    n0 = __builtin_amdgcn_readfirstlane(n0);
    int n1 = n0 + 1;                        // N_NODES even -> always valid
    int lane = threadIdx.x & 63;
    int4 ni0 = nodeinfo[n0];
    int4 ni1 = nodeinfo[n1];
    int su0 = __builtin_amdgcn_readfirstlane(ni0.x);
    int dp0 = (__builtin_amdgcn_readfirstlane(ni0.y) + 3) & ~3;
    int su1 = __builtin_amdgcn_readfirstlane(ni1.x);
    int dp1 = (__builtin_amdgcn_readfirstlane(ni1.y) + 3) & ~3;
    float a0 = 0.f, a1 = 0.f;
    gather_lane2(g, packed, su0, dp0, su1, dp1, lane, a0, a1);
    float m0 = __int_as_float(ni0.z);
    float m1 = __int_as_float(ni1.z);
    gn[((unsigned)n0 << 6) + lane] = f2bf(a0 * m0 * m0);
    gn[((unsigned)n1 << 6) + lane] = f2bf(a1 * m1 * m1);
}

// Fused layer-3 + epilogue, batch nodes only (lane = dim):
// out[slot] = 0.25*( x[n] + rn*g1[n] + rn*g2[n] + nm*sum_{s in N(n)} g2[s] ).
__global__ void __launch_bounds__(256)
lgcn_final(const float* __restrict__ ue, const float* __restrict__ ie,
           const bf16_t* __restrict__ g1, const bf16_t* __restrict__ g2,
           const int4* __restrict__ nodeinfo, const int* __restrict__ packed,
           const int* __restrict__ uid, const int* __restrict__ iid,
           float* __restrict__ out) {
    int slot = blockIdx.x * 4 + (threadIdx.x >> 6);
    if (slot >= 2 * BATCH) return;
    slot = __builtin_amdgcn_readfirstlane(slot);
    int lane = threadIdx.x & 63;
    int isItem = slot >= BATCH;
    int b = isItem ? (slot - BATCH) : slot;
    int node = isItem ? (N_USERS + iid[b]) : uid[b];
    node = __builtin_amdgcn_readfirstlane(node);
    int4 ni = nodeinfo[node];
    int su = __builtin_amdgcn_readfirstlane(ni.x);
    int du = __builtin_amdgcn_readfirstlane(ni.y);
    int dp = (du + 3) & ~3;
    float acc = gather_lane(g2, packed, su, dp, lane);
    const float* xb = isItem ? (ie + ((unsigned)(node - N_USERS) << 6))
                             : (ue + ((unsigned)node << 6));
    float x = xb[lane];
    float a1 = bf2f(g1[((unsigned)node << 6) + lane]);
    float a2 = bf2f(g2[((unsigned)node << 6) + lane]);
    float rn = __int_as_float(ni.w);
    float nm = __int_as_float(ni.z);
    out[((unsigned)slot << 6) + lane] = 0.25f * (x + rn * (a1 + a2) + nm * acc);
}

// --- Launch ----------------------------------------------------------------

extern "C" void kernel_launch(void* const* d_in, const int* in_sizes, int n_in,
                              void* d_out, int out_size, void* d_ws, size_t ws_size,
                              hipStream_t stream) {
    const float* ue  = (const float*)d_in[0];
    const float* ie  = (const float*)d_in[1];
    const int*   ei  = (const int*)d_in[3];
    const int*   uid = (const int*)d_in[4];
    const int*   iid = (const int*)d_in[5];
    float* out = (float*)d_out;

    const int E  = in_sizes[2];     // 2,000,000 directed edges
    const int EH = E / 2;           // 1,000,000 undirected pairs
    const int* row = ei;            // first-half src = user ids
    const int* col = ei + E;        // first-half dst = item node ids

    const int nblk = (EH + PAIRS_PER_BLK - 1) / PAIRS_PER_BLK;   // 489

    // Workspace carve-up (256-B aligned), ~58 MB total.
    char* p = (char*)d_ws;
    size_t off = 0;
    auto carve = [&](size_t bytes) -> char* {
        char* r = p + off;
        off += (bytes + 255) & ~(size_t)255;
        return r;
    };
    const size_t nodeBf16 = (size_t)(N_NODES + 1) * DIM * sizeof(bf16_t); // +zero row
    bf16_t* gA       = (bf16_t*)carve(nodeBf16);
    bf16_t* gB       = (bf16_t*)carve(nodeBf16);
    int4*   nodeinfo = (int4*)carve((size_t)N_NODES * sizeof(int4));       // 2.4 MB
    int*    pos      = (int*)carve((size_t)nblk * (NB + 1) * sizeof(int)); // 1.15 MB
    int*    binned   = (int*)carve((size_t)nblk * STRIP * sizeof(int));    // 8 MB
    int*    packed   = (int*)carve((size_t)NB * CAP * sizeof(int));        // 19.2 MB
    (void)ws_size;

    // 1) Strip sort.
    lgcn_bin<<<nblk, 256, 0, stream>>>(row, col, pos, binned, EH);
    // 2) Per-bucket CSR (flattened gather, direct scatter) + fused g0 init.
    lgcn_build_csr<<<NB, 256, 0, stream>>>(pos, binned, nodeinfo, packed,
                                           ue, ie, gA, gB, nblk);
    // 3) Two full pulls (2 nodes/wave, lane=dim), then batch-only epilogue.
    const int pullGrid = (N_NODES / 2 + 3) / 4;    // 18750
    lgcn_pull<<<pullGrid, 256, 0, stream>>>(gA, nodeinfo, packed, gB);  // g1 = gB
    lgcn_pull<<<pullGrid, 256, 0, stream>>>(gB, nodeinfo, packed, gA);  // g2 = gA
    lgcn_final<<<(2 * BATCH + 3) / 4, 256, 0, stream>>>(
        ue, ie, gB, gA, nodeinfo, packed, uid, iid, out);
}

// Round 14
// 222.626 us; speedup vs baseline: 1.0533x; 1.0533x over previous
//
#include <hip/hip_runtime.h>

// LightGCN encoder on MI355X — round 21 (revert to measured best).
// Round 20 post-mortem: 2-node interleaved pull REGRESSED 44.6 -> 52.2 us
// (guarded dual-stream loop serialized at s_waitcnt; VGPR 12 => compiler
// kept FEWER loads in flight; grid halved => fewer total outstanding
// requests). Pre-committed threshold tripped: the 1-node lane=dim pull at
// 44.5 us IS the random-row request-capacity floor (bracketed from above by
// 48.5 / 45.4 / 52.2 us alternatives).
// This round: exact revert to the round-18 structure (223.7 us; best overall
// 223.2 within noise). If this reproduces ~223 us, declare ROOFLINE:
//   - pulls 2 x 44.5 us at the gather service floor
//   - persistent fusion closed by per-XCD L2 non-coherence (r11/r16)
//   - preprocessing attacks all within +/-2 us (r15/r18/r19)
//   - dispatch-count reduction net ~0 (r12)
#define N_USERS 100000
#define N_NODES 150000
#define DIM 64
#define BATCH 4096
#define BSHIFT 8
#define BUCKET 256
#define NB 586                 // ceil(150000 / 256) buckets
#define NBP 768                // padded bucket count for the 3-per-thread scan
#define PAIRS_PER_BLK 2048     // undirected pairs per binning block
#define STRIP 4096             // directed edges (words) per strip
#define CAPSHIFT 13
#define CAP (1 << CAPSHIFT)    // packed slots per bucket (max ~5.4K used)

typedef unsigned short bf16_t;

static __device__ __forceinline__ float bf2f(bf16_t h) {
    return __uint_as_float(((unsigned)h) << 16);
}
static __device__ __forceinline__ bf16_t f2bf(float f) {  // round-nearest-even
    unsigned u = __float_as_uint(f);
    return (bf16_t)((u + 0x7FFFu + ((u >> 16) & 1u)) >> 16);
}

// --- Strip sort: LDS counting-sort of 4096 directed edges by bucket --------
// binned word = (local_dst[8b]<<18)|src. pos[k*(NB+1)+b] = run start of
// bucket b in strip k; pos[k*(NB+1)+NB] = edge count of strip k.
__global__ void __launch_bounds__(256)
lgcn_bin(const int* __restrict__ row, const int* __restrict__ col,
         int* __restrict__ pos, int* __restrict__ binned, int EH) {
    __shared__ int cnt[NBP];
    __shared__ int sA[256], sB[256];
    __shared__ int base[NB + 2];
    __shared__ int stage[STRIP];
    int tid = threadIdx.x;
    int k = blockIdx.x;
    cnt[tid] = 0; cnt[tid + 256] = 0; cnt[tid + 512] = 0;
    __syncthreads();
    int e0 = k * PAIRS_PER_BLK;
    int e1 = min(EH, e0 + PAIRS_PER_BLK);
    int n = e1 - e0;                           // pairs (multiple of 4)
    int nq = n >> 2;
    const int4* r4 = (const int4*)(row + e0);
    const int4* c4 = (const int4*)(col + e0);
    for (int q = tid; q < nq; q += 256) {
        int4 r = r4[q]; int4 c = c4[q];
        atomicAdd(&cnt[r.x >> BSHIFT], 1); atomicAdd(&cnt[c.x >> BSHIFT], 1);
        atomicAdd(&cnt[r.y >> BSHIFT], 1); atomicAdd(&cnt[c.y >> BSHIFT], 1);
        atomicAdd(&cnt[r.z >> BSHIFT], 1); atomicAdd(&cnt[c.z >> BSHIFT], 1);
        atomicAdd(&cnt[r.w >> BSHIFT], 1); atomicAdd(&cnt[c.w >> BSHIFT], 1);
    }
    __syncthreads();
    // Exclusive scan over NBP buckets, 3 per thread.
    int c0 = cnt[3 * tid], c1 = cnt[3 * tid + 1], c2 = cnt[3 * tid + 2];
    int s = c0 + c1 + c2;
    sA[tid] = s;
    __syncthreads();
    int* c_ = sA; int* n_ = sB;
    for (int off = 1; off < 256; off <<= 1) {
        n_[tid] = (tid >= off) ? c_[tid] + c_[tid - off] : c_[tid];
        __syncthreads();
        int* t = c_; c_ = n_; n_ = t;
    }
    int excl = c_[tid] - s;
    if (3 * tid     <= NB) base[3 * tid]     = excl;
    if (3 * tid + 1 <= NB) base[3 * tid + 1] = excl + c0;
    if (3 * tid + 2 <= NB) base[3 * tid + 2] = excl + c0 + c1;
    __syncthreads();
    // pos table (coalesced) + LDS cursors (reuse cnt).
    for (int i = tid; i <= NB; i += 256) {
        pos[k * (NB + 1) + i] = base[i];
        cnt[i] = base[i];
    }
    __syncthreads();
    // LDS scatter (re-read pairs; L2-hot).
    for (int q = tid; q < nq; q += 256) {
        int4 r = r4[q]; int4 c = c4[q];
        int rr[4] = { r.x, r.y, r.z, r.w };
        int cc[4] = { c.x, c.y, c.z, c.w };
#pragma unroll
        for (int j = 0; j < 4; ++j) {
            int p1 = atomicAdd(&cnt[cc[j] >> BSHIFT], 1);
            stage[p1] = ((cc[j] & (BUCKET - 1)) << 18) | rr[j];
            int p2 = atomicAdd(&cnt[rr[j] >> BSHIFT], 1);
            stage[p2] = ((rr[j] & (BUCKET - 1)) << 18) | cc[j];
        }
    }
    __syncthreads();
    // Coalesced strip write-out.
    int m4 = (2 * n) >> 2;
    int4* dst = (int4*)(binned + k * STRIP);
    const int4* st4 = (const int4*)stage;
    for (int j = tid; j < m4; j += 256) dst[j] = st4[j];
}

// --- Per-bucket padded CSR + fused g0 init ---------------------------------
// Phase A: flattened gather (runStart/runAddr + binary search, independent
// coalesced-ish loads). Phase B: hist/scan/scatter + g0 init.
// Node segments padded to multiple of 4; pad slots = N_NODES (zero row).
// nodeinfo = {start, deg, bits(1/sqrt(da)), bits(sqrt(da))}.
__global__ void __launch_bounds__(256)
lgcn_build_csr(const int* __restrict__ pos, const int* __restrict__ binned,
               int4* __restrict__ nodeinfo, int* __restrict__ packed,
               const float* __restrict__ ue, const float* __restrict__ ie,
               bf16_t* __restrict__ g0, bf16_t* __restrict__ g1, int nblk) {
    __shared__ int stage[CAP];     // gathered edges of this bucket (32 KB)
    __shared__ int ovl[1025];      // phase A: runStart[513] + runAddr[512]
                                   // phase B: hist[256] + cur[256]
    __shared__ int sA[256], sB[256];
    int b = blockIdx.x;
    int tid = threadIdx.x;
    int gb = b << CAPSHIFT;        // this block's private packed region
    int* runStart = ovl;
    int* runAddr  = ovl + 513;
    // Runs for strips 2*tid and 2*tid+1 (adjacent -> contiguous flat order).
    int s0 = 2 * tid, s1 = 2 * tid + 1;
    int a0 = 0, l0 = 0, a1 = 0, l1 = 0;
    if (s0 < nblk) {
        const int* pk = pos + s0 * (NB + 1) + b;
        a0 = pk[0]; l0 = pk[1] - a0;
    }
    if (s1 < nblk) {
        const int* pk = pos + s1 * (NB + 1) + b;
        a1 = pk[0]; l1 = pk[1] - a1;
    }
    runAddr[s0] = s0 * STRIP + a0;
    runAddr[s1] = s1 * STRIP + a1;
    int u = l0 + l1;
    sA[tid] = u;
    __syncthreads();
    int* c_ = sA; int* n_ = sB;
    for (int off = 1; off < 256; off <<= 1) {
        n_[tid] = (tid >= off) ? c_[tid] + c_[tid - off] : c_[tid];
        __syncthreads();
        int* t = c_; c_ = n_; n_ = t;
    }
    int base2 = c_[tid] - u;
    runStart[s0] = base2;
    runStart[s1] = base2 + l0;
    int Eb = c_[255];
    if (tid == 0) runStart[512] = Eb;
    __syncthreads();
    // Flattened gather: independent loads, consecutive j coalesce in runs.
    for (int j = tid; j < Eb; j += 256) {
        int lo = 0;                           // largest s: runStart[s] <= j
#pragma unroll
        for (int step = 256; step > 0; step >>= 1) {
            int mid = lo + step;
            if (mid <= 511 && runStart[mid] <= j) lo = mid;
        }
        stage[j] = binned[runAddr[lo] + (j - runStart[lo])];
    }
    __syncthreads();                          // runStart/runAddr dead
    int* hist = ovl;                          // overlay phase B
    int* cur  = ovl + 256;
    hist[tid] = 0;
    __syncthreads();
    for (int j = tid; j < Eb; j += 256)
        atomicAdd(&hist[stage[j] >> 18], 1);
    __syncthreads();
    int deg = hist[tid];
    int degp = (deg + 3) & ~3;               // padded segment length
    sA[tid] = degp;
    __syncthreads();
    int* c2 = sA; int* n2 = sB;
    for (int off = 1; off < 256; off <<= 1) {
        n2[tid] = (tid >= off) ? c2[tid] + c2[tid - off] : c2[tid];
        __syncthreads();
        int* t = c2; c2 = n2; n2 = t;
    }
    int startLoc = c2[tid] - degp;           // local, int4-aligned
    cur[tid] = startLoc;
    int node = (b << BSHIFT) + tid;
    float da = (deg == 0) ? 1.0f : (float)deg;
    float sq = sqrtf(da);
    float nm = 1.0f / sq;
    if (node < N_NODES) {
        int4 ni;
        ni.x = gb + startLoc;
        ni.y = deg;
        ni.z = __float_as_int(nm);
        ni.w = __float_as_int(sq);
        nodeinfo[node] = ni;
    }
    __syncthreads();                          // all hist reads done
    hist[tid] = __float_as_int(nm);           // reuse hist as norm table
    // Pad slots -> zero row (block-owned region; disjoint from scatter).
    for (int kk = deg; kk < degp; ++kk)
        packed[gb + startLoc + kk] = N_NODES;
    // Direct global scatter into the block's private bucket region.
    for (int j = tid; j < Eb; j += 256) {
        int w = stage[j];
        int p = atomicAdd(&cur[w >> 18], 1);  // LDS atomic
        packed[gb + p] = w & 0x3FFFF;
    }
    // --- Fused g0 init for this bucket's nodes (flat chunk range is
    // contiguous: t = b*4096 + i, i in [0, nloc*16)). -----------------------
    int firstNode = b << BSHIFT;
    int nloc = min(BUCKET, N_NODES - firstNode);
    const int nU16 = N_USERS * (DIM / 4);
    int t0 = firstNode * (DIM / 4);
    for (int i = tid; i < nloc * (DIM / 4); i += 256) {
        int t = t0 + i;
        float4 x = (t < nU16) ? ((const float4*)ue)[t]
                              : ((const float4*)ie)[t - nU16];
        float nrm = __int_as_float(hist[i >> 4]);
        ushort4 o;
        o.x = f2bf(x.x * nrm); o.y = f2bf(x.y * nrm);
        o.z = f2bf(x.z * nrm); o.w = f2bf(x.w * nrm);
        ((ushort4*)g0)[t] = o;
    }
    if (b == 0 && tid < 32) {                 // zero rows in both buffers
        const int nT = N_NODES * (DIM / 4);
        if (tid < 16) ((ushort4*)g0)[nT + tid] = make_ushort4(0, 0, 0, 0);
        else          ((ushort4*)g1)[nT + tid - 16] = make_ushort4(0, 0, 0, 0);
    }
}

// --- Propagation (lane = dim) ----------------------------------------------

// Sum rows of g for edges [su, su+dp): wave-uniform su/dp (SGPR), scalar
// edge-quad loads, saddr row reads with loop-invariant lane offset.
static __device__ __forceinline__ float
gather_lane(const bf16_t* __restrict__ g, const int* __restrict__ packed,
            int su, int dp, int lane) {
    float acc = 0.f;
    const int4* p4 = (const int4*)(packed + su);
    int k = 0;
    for (; k + 8 <= dp; k += 8) {            // 8 independent row loads
        int4 ea = p4[k >> 2];
        int4 eb = p4[(k >> 2) + 1];
        const bf16_t* r0 = g + ((unsigned)ea.x << 6);
        const bf16_t* r1 = g + ((unsigned)ea.y << 6);
        const bf16_t* r2 = g + ((unsigned)ea.z << 6);
        const bf16_t* r3 = g + ((unsigned)ea.w << 6);
        const bf16_t* r4 = g + ((unsigned)eb.x << 6);
        const bf16_t* r5 = g + ((unsigned)eb.y << 6);
        const bf16_t* r6 = g + ((unsigned)eb.z << 6);
        const bf16_t* r7 = g + ((unsigned)eb.w << 6);
        float v0 = bf2f(r0[lane]); float v1 = bf2f(r1[lane]);
        float v2 = bf2f(r2[lane]); float v3 = bf2f(r3[lane]);
        float v4 = bf2f(r4[lane]); float v5 = bf2f(r5[lane]);
        float v6 = bf2f(r6[lane]); float v7 = bf2f(r7[lane]);
        acc += ((v0 + v1) + (v2 + v3)) + ((v4 + v5) + (v6 + v7));
    }
    if (k < dp) {                            // tail quad (dp % 8 == 4)
        int4 ea = p4[k >> 2];
        const bf16_t* r0 = g + ((unsigned)ea.x << 6);
        const bf16_t* r1 = g + ((unsigned)ea.y << 6);
        const bf16_t* r2 = g + ((unsigned)ea.z << 6);
        const bf16_t* r3 = g + ((unsigned)ea.w << 6);
        float v0 = bf2f(r0[lane]); float v1 = bf2f(r1[lane]);
        float v2 = bf2f(r2[lane]); float v3 = bf2f(r3[lane]);
        acc += (v0 + v1) + (v2 + v3);
    }
    return acc;
}

// Full pull: gn[n] = bf16( norm[n]^2 * sum_{s in N(n)} g[s] ). One node/wave.
__global__ void __launch_bounds__(256)
lgcn_pull(const bf16_t* __restrict__ g, const int4* __restrict__ nodeinfo,
          const int* __restrict__ packed, bf16_t* __restrict__ gn) {
    int n = blockIdx.x * 4 + (threadIdx.x >> 6);
    if (n >= N_NODES) return;
    n = __builtin_amdgcn_readfirstlane(n);
    int lane = threadIdx.x & 63;
    int4 ni = nodeinfo[n];
    int su = __builtin_amdgcn_readfirstlane(ni.x);
    int du = __builtin_amdgcn_readfirstlane(ni.y);
    int dp = (du + 3) & ~3;
    float acc = gather_lane(g, packed, su, dp, lane);
    float nm = __int_as_float(ni.z);
    gn[((unsigned)n << 6) + lane] = f2bf(acc * nm * nm);
}

// Fused layer-3 + epilogue, batch nodes only (lane = dim):
// out[slot] = 0.25*( x[n] + rn*g1[n] + rn*g2[n] + nm*sum_{s in N(n)} g2[s] ).
__global__ void __launch_bounds__(256)
lgcn_final(const float* __restrict__ ue, const float* __restrict__ ie,
           const bf16_t* __restrict__ g1, const bf16_t* __restrict__ g2,
           const int4* __restrict__ nodeinfo, const int* __restrict__ packed,
           const int* __restrict__ uid, const int* __restrict__ iid,
           float* __restrict__ out) {
    int slot = blockIdx.x * 4 + (threadIdx.x >> 6);
    if (slot >= 2 * BATCH) return;
    slot = __builtin_amdgcn_readfirstlane(slot);
    int lane = threadIdx.x & 63;
    int isItem = slot >= BATCH;
    int b = isItem ? (slot - BATCH) : slot;
    int node = isItem ? (N_USERS + iid[b]) : uid[b];
    node = __builtin_amdgcn_readfirstlane(node);
    int4 ni = nodeinfo[node];
    int su = __builtin_amdgcn_readfirstlane(ni.x);
    int du = __builtin_amdgcn_readfirstlane(ni.y);
    int dp = (du + 3) & ~3;
    float acc = gather_lane(g2, packed, su, dp, lane);
    const float* xb = isItem ? (ie + ((unsigned)(node - N_USERS) << 6))
                             : (ue + ((unsigned)node << 6));
    float x = xb[lane];
    float a1 = bf2f(g1[((unsigned)node << 6) + lane]);
    float a2 = bf2f(g2[((unsigned)node << 6) + lane]);
    float rn = __int_as_float(ni.w);
    float nm = __int_as_float(ni.z);
    out[((unsigned)slot << 6) + lane] = 0.25f * (x + rn * (a1 + a2) + nm * acc);
}

// --- Launch ----------------------------------------------------------------

extern "C" void kernel_launch(void* const* d_in, const int* in_sizes, int n_in,
                              void* d_out, int out_size, void* d_ws, size_t ws_size,
                              hipStream_t stream) {
    const float* ue  = (const float*)d_in[0];
    const float* ie  = (const float*)d_in[1];
    const int*   ei  = (const int*)d_in[3];
    const int*   uid = (const int*)d_in[4];
    const int*   iid = (const int*)d_in[5];
    float* out = (float*)d_out;

    const int E  = in_sizes[2];     // 2,000,000 directed edges
    const int EH = E / 2;           // 1,000,000 undirected pairs
    const int* row = ei;            // first-half src = user ids
    const int* col = ei + E;        // first-half dst = item node ids

    const int nblk = (EH + PAIRS_PER_BLK - 1) / PAIRS_PER_BLK;   // 489

    // Workspace carve-up (256-B aligned), ~58 MB total.
    char* p = (char*)d_ws;
    size_t off = 0;
    auto carve = [&](size_t bytes) -> char* {
        char* r = p + off;
        off += (bytes + 255) & ~(size_t)255;
        return r;
    };
    const size_t nodeBf16 = (size_t)(N_NODES + 1) * DIM * sizeof(bf16_t); // +zero row
    bf16_t* gA       = (bf16_t*)carve(nodeBf16);
    bf16_t* gB       = (bf16_t*)carve(nodeBf16);
    int4*   nodeinfo = (int4*)carve((size_t)N_NODES * sizeof(int4));       // 2.4 MB
    int*    pos      = (int*)carve((size_t)nblk * (NB + 1) * sizeof(int)); // 1.15 MB
    int*    binned   = (int*)carve((size_t)nblk * STRIP * sizeof(int));    // 8 MB
    int*    packed   = (int*)carve((size_t)NB * CAP * sizeof(int));        // 19.2 MB
    (void)ws_size;

    // 1) Strip sort.
    lgcn_bin<<<nblk, 256, 0, stream>>>(row, col, pos, binned, EH);
    // 2) Per-bucket CSR (flattened gather, direct scatter) + fused g0 init.
    lgcn_build_csr<<<NB, 256, 0, stream>>>(pos, binned, nodeinfo, packed,
                                           ue, ie, gA, gB, nblk);
    // 3) Two full pulls (1 node/wave, lane=dim), then batch-only epilogue.
    const int pullGrid = (N_NODES + 3) / 4;        // 37500
    lgcn_pull<<<pullGrid, 256, 0, stream>>>(gA, nodeinfo, packed, gB);  // g1 = gB
    lgcn_pull<<<pullGrid, 256, 0, stream>>>(gB, nodeinfo, packed, gA);  // g2 = gA
    lgcn_final<<<(2 * BATCH + 3) / 4, 256, 0, stream>>>(
        ue, ie, gB, gA, nodeinfo, packed, uid, iid, out);
}